// Round 20
// baseline (189.501 us; speedup 1.0000x reference)
//
#include <hip/hip_runtime.h>
#include <hip/hip_bf16.h>

// Problem constants
#define BB   128
#define SS   168
#define DM   128
#define LL   2
#define II   256
#define NN   16
#define RR   8
#define KK   4
#define PP   24
#define MROWS (BB*SS)   // 21504
#define NCH  12         // scan chunks
#define TCH  14         // SS / NCH (fits one MFMA M=16 tile)
#define LOG2E 1.4426950408889634f

// bf16 fragment pool: xp_w (24/layer) + in_w (128/layer) + out_w (64/layer)
#define XPF  24
#define INF  128
#define OUTF 64
#define FR_TOT (LL*(XPF+INF+OUTF))   // 432

typedef __attribute__((ext_vector_type(8))) short bf16x8;
typedef __attribute__((ext_vector_type(4))) short bf16x4;
typedef __attribute__((ext_vector_type(4))) float f32x4;

__device__ __forceinline__ float wave_sum(float x) {
#pragma unroll
    for (int off = 32; off > 0; off >>= 1) x += __shfl_xor(x, off);
    return x;
}
__device__ __forceinline__ float fexp2(float x) {   // v_exp_f32 (2^x)
    return __builtin_amdgcn_exp2f(x);
}
__device__ __forceinline__ float siluf(float x) {   // fast: rcp + exp2
    return x * __builtin_amdgcn_rcpf(1.f + fexp2(-LOG2E * x));
}
__device__ __forceinline__ float softplusf(float x) {
    return (x > 20.f) ? x : __logf(1.f + __expf(x));
}
__device__ __forceinline__ short f2bf(float x) {   // RNE f32 -> bf16
    unsigned u = __builtin_bit_cast(unsigned, x);
    u = (u + 0x7FFFu + ((u >> 16) & 1u)) >> 16;
    return (short)u;
}
// HW packed f32->bf16 (RNE): 4 floats -> bf16x4 (R5-validated cvt pattern)
__device__ __forceinline__ bf16x4 cvt4v(float4 a) {
    unsigned u0, u1;
    asm("v_cvt_pk_bf16_f32 %0, %1, %2" : "=v"(u0) : "v"(a.x), "v"(a.y));
    asm("v_cvt_pk_bf16_f32 %0, %1, %2" : "=v"(u1) : "v"(a.z), "v"(a.w));
    union { unsigned u[2]; bf16x4 v; } r;
    r.u[0] = u0; r.u[1] = u1;
    return r.v;
}
// HW packed f32->bf16 (RNE): 8 floats -> bf16x8 (validated R2/R5/R10)
__device__ __forceinline__ bf16x8 cvt8v(float4 a, float4 b) {
    unsigned u0, u1, u2, u3;
    asm("v_cvt_pk_bf16_f32 %0, %1, %2" : "=v"(u0) : "v"(a.x), "v"(a.y));
    asm("v_cvt_pk_bf16_f32 %0, %1, %2" : "=v"(u1) : "v"(a.z), "v"(a.w));
    asm("v_cvt_pk_bf16_f32 %0, %1, %2" : "=v"(u2) : "v"(b.x), "v"(b.y));
    asm("v_cvt_pk_bf16_f32 %0, %1, %2" : "=v"(u3) : "v"(b.z), "v"(b.w));
    union { unsigned u[4]; bf16x8 v; } r;
    r.u[0] = u0; r.u[1] = u1; r.u[2] = u2; r.u[3] = u3;
    return r.v;
}

// ---------------------------------------------------------------------------
// hn = bf16(h * rsqrt(mean(h^2)+eps) * mnw) — rowscale via wave_sum
// (R12-validated). One wave per row.
// ---------------------------------------------------------------------------
__global__ __launch_bounds__(256)
void hn_kernel(const float* __restrict__ h, const float* __restrict__ mnw,
               short* __restrict__ hn)
{
    const int row  = blockIdx.x * 4 + (threadIdx.x >> 6);
    const int lane = threadIdx.x & 63;
    const float2 v = *(const float2*)&h[(size_t)row * DM + lane * 2];
    const float ss = wave_sum(v.x * v.x + v.y * v.y);
    const float rsv = rsqrtf(ss * (1.f / DM) + 1e-5f);
    const float2 w = *(const float2*)&mnw[lane * 2];
    short2 o;
    o.x = f2bf(v.x * rsv * w.x);
    o.y = f2bf(v.y * rsv * w.y);
    *(short2*)&hn[(size_t)row * DM + lane * 2] = o;
}

// ---------------------------------------------------------------------------
// One-shot weight swizzle to MFMA B-fragment order (R10/R13-validated).
// Pool: [xp l0|l1 (24 ea)][inw l0|l1 (128 ea)][outw l0|l1 (64 ea)].
// ---------------------------------------------------------------------------
__global__ __launch_bounds__(256)
void cvtw_kernel(const float* __restrict__ xw, const float* __restrict__ inw,
                 const float* __restrict__ outw, short* __restrict__ dst)
{
    const int tid = blockIdx.x * 256 + threadIdx.x;
    if (tid >= FR_TOT * 64) return;
    const int lane = tid & 63;
    const int fg = tid >> 6;
    float4 v0 = {0.f, 0.f, 0.f, 0.f}, v1 = {0.f, 0.f, 0.f, 0.f};
    if (fg < LL * XPF) {
        const int l = fg / XPF, f = fg % XPF;
        const int nt = f >> 3, kt = f & 7;
        const int row = nt * 16 + (lane & 15);
        const int kc = kt * 32 + (lane >> 4) * 8;
        if (row < 40) {
            const float* s = xw + ((size_t)l * 40 + row) * II + kc;
            v0 = *(const float4*)s;
            v1 = *(const float4*)(s + 4);
        }
    } else if (fg < LL * (XPF + INF)) {
        const int g = fg - LL * XPF;
        const int l = g / INF, fi = g % INF;
        const int nt = fi >> 2, kt = fi & 3;
        const int row = nt * 16 + (lane & 15);          // 0..511
        const int kc = kt * 32 + (lane >> 4) * 8;       // 0..127
        const float* s = inw + ((size_t)l * 2 * II + row) * DM + kc;
        v0 = *(const float4*)s;
        v1 = *(const float4*)(s + 4);
    } else {
        const int g = fg - LL * (XPF + INF);
        const int l = g / OUTF, fo = g % OUTF;
        const int nt = fo >> 3, kt = fo & 7;            // nt 0..7, kt 0..7
        const int row = nt * 16 + (lane & 15);          // 0..127
        const int kc = kt * 32 + (lane >> 4) * 8;       // 0..255
        const float* s = outw + ((size_t)l * DM + row) * II + kc;
        v0 = *(const float4*)s;
        v1 = *(const float4*)(s + 4);
    }
    *(bf16x8*)(dst + ((size_t)tid) * 8) = cvt8v(v0, v1);
}

// ---------------------------------------------------------------------------
// bf16-MFMA GEMM — R11-exact schedule (fusion only).  R20: software
// pack4/pack8 replaced by HW v_cvt_pk (RNE-identical, R2/R5-validated) —
// cuts ~40 pack-VALU per thread per k-tile.
// ---------------------------------------------------------------------------
#define LDT 40
template<bool ACCUM>
__global__ __launch_bounds__(256)
void gemm_mfma(const float* __restrict__ A, const short* __restrict__ Abf,
               const float* __restrict__ W, int K,
               const float* __restrict__ A2, const float* __restrict__ W2, int K2,
               const float* __restrict__ bias,
               const float* __restrict__ r1x, const float* __restrict__ r1w,
               float* __restrict__ C, int ldc)
{
    __shared__ __align__(16) short Asl[32 * LDT];
    __shared__ __align__(16) short Bsl[64 * LDT];
    const int bm = blockIdx.x * 32;
    const int bn = blockIdx.y * 64;
    const int t  = threadIdx.x;
    const int lane = t & 63;
    const int wave = t >> 6;
    const int wr = wave >> 1, wc = wave & 1;
    const int lrow = lane & 15;
    const int lk   = (lane >> 4) * 8;

    f32x4 acc[2];
    acc[0] = (f32x4){0.f, 0.f, 0.f, 0.f};
    acc[1] = (f32x4){0.f, 0.f, 0.f, 0.f};

    const int arow = t >> 3, ak = (t & 7) * 4;    // A: 32 rows x 32 k
    const int brow = t >> 2, bk = (t & 3) * 8;    // B: 64 rows x 32 k

    float av[4], bv[8];
    bf16x4 avb;

#pragma unroll 1
    for (int pass = 0; pass < 2; ++pass) {
        const bool useBf = (pass == 0) && (Abf != nullptr);
        const float* Ap = pass ? A2 : A;
        if (!Ap && !useBf) continue;
        const float* Wp = pass ? W2 : W;
        const int    Kp = pass ? K2 : K;
        const short* abptr = useBf ? Abf + (size_t)(bm + arow) * Kp + ak : nullptr;
        const float* aptr  = useBf ? nullptr : Ap + (size_t)(bm + arow) * Kp + ak;
        const float* bptr = Wp + (size_t)(bn + brow) * Kp + bk;

        // prologue load (k0 = 0)
        if (useBf) avb = *(const bf16x4*)(abptr);
        else       *(float4*)&av[0] = *(const float4*)(aptr);
        *(float4*)&bv[0] = *(const float4*)(bptr);
        *(float4*)&bv[4] = *(const float4*)(bptr + 4);

#pragma unroll 1
        for (int k0 = 0; k0 < Kp; k0 += 32) {
            __syncthreads();   // previous iteration's LDS reads done
            if (useBf) *(bf16x4*)&Asl[arow * LDT + ak] = avb;
            else       *(bf16x4*)&Asl[arow * LDT + ak] = cvt4v(*(const float4*)&av[0]);
            *(bf16x8*)&Bsl[brow * LDT + bk] =
                cvt8v(*(const float4*)&bv[0], *(const float4*)&bv[4]);
            __syncthreads();
            const int kn = k0 + 32;
            if (kn < Kp) {   // prefetch next tile while MFMA runs
                if (useBf) avb = *(const bf16x4*)(abptr + kn);
                else       *(float4*)&av[0] = *(const float4*)(aptr + kn);
                *(float4*)&bv[0] = *(const float4*)(bptr + kn);
                *(float4*)&bv[4] = *(const float4*)(bptr + kn + 4);
            }
            const bf16x8 af = *(const bf16x8*)&Asl[(wr * 16 + lrow) * LDT + lk];
            bf16x8 bfr[2];
#pragma unroll
            for (int ni = 0; ni < 2; ++ni)
                bfr[ni] = *(const bf16x8*)&Bsl[(wc * 32 + ni * 16 + lrow) * LDT + lk];
#pragma unroll
            for (int ni = 0; ni < 2; ++ni)
                acc[ni] = __builtin_amdgcn_mfma_f32_16x16x32_bf16(af, bfr[ni], acc[ni], 0, 0, 0);
        }
    }

    // epilogue
#pragma unroll
    for (int r = 0; r < 4; ++r) {
        const int row = bm + wr * 16 + (lane >> 4) * 4 + r;
        const float xl = r1x ? r1x[row] : 0.f;
#pragma unroll
        for (int ni = 0; ni < 2; ++ni) {
            const int col = bn + wc * 32 + ni * 16 + lrow;
            float v = acc[ni][r];
            if (bias) v += bias[col];
            if (r1x)  v += xl * r1w[col];
            float* cp = &C[(size_t)row * ldc + col];
            if (ACCUM) v += *cp;
            *cp = v;
        }
    }
}

// ---------------------------------------------------------------------------
// Fused hs-GEMM + conv + x_proj(MFMA) + scanA per (b, chunk) — R13/R14/R17
// validated (exp2 with prescaled Ar2).
// ---------------------------------------------------------------------------
__global__ __launch_bounds__(256)
void fusedA_kernel(const short* __restrict__ hn, const float* __restrict__ cw,
                   const float* __restrict__ cb, const short* __restrict__ inws,
                   const short* __restrict__ xws, const float* __restrict__ inb,
                   const float* __restrict__ dtw, const float* __restrict__ dtb,
                   const float* __restrict__ A_log,
                   float* __restrict__ ut, float* __restrict__ sp,
                   float* __restrict__ dtsum_g, float* __restrict__ q)
{
    __shared__ float hsl[17][II + 4];    // hs tile incl. 3 halo rows
    __shared__ float uts[TCH][II + 4];   // 14 x 260
    __shared__ float lsp[TCH * 40];
    const int b = blockIdx.x;
    const int ch = blockIdx.y;
    const int i = threadIdx.x;
    const int s0 = ch * TCH;
    const int lane = i & 63;
    const int wv = i >> 6;
    const int lrow = lane & 15;
    const int lkg = (lane >> 4) * 8;
    const int r0 = (lane >> 4) * 4;

    // ---- phase 0: hs tile via MFMA (17 rows x 256 cols, K=128) ----
    {
        const short* hnb = hn + (size_t)b * SS * DM;
#pragma unroll
        for (int mt = 0; mt < 2; ++mt) {
            const int ma = mt * 16 + lrow;       // A row within tile
            const int rga = s0 - 3 + ma;
            const bool va = (ma < 17) && (rga >= 0);
            bf16x8 af[4];
#pragma unroll
            for (int kt = 0; kt < 4; ++kt) {
                if (va) af[kt] = *(const bf16x8*)(hnb + (size_t)rga * DM + kt * 32 + lkg);
                else { bf16x8 z = {0,0,0,0,0,0,0,0}; af[kt] = z; }
            }
#pragma unroll
            for (int j = 0; j < 4; ++j) {
                const int nt = wv * 4 + j;       // 0..15 (hs cols)
                f32x4 acc = (f32x4){0.f, 0.f, 0.f, 0.f};
#pragma unroll
                for (int kt = 0; kt < 4; ++kt) {
                    const bf16x8 bf = *(const bf16x8*)(inws + ((size_t)(nt * 4 + kt) * 64 + lane) * 8);
                    acc = __builtin_amdgcn_mfma_f32_16x16x32_bf16(af[kt], bf, acc, 0, 0, 0);
                }
                const int n = nt * 16 + lrow;
                const float bn_ = inb[n];
#pragma unroll
                for (int r = 0; r < 4; ++r) {
                    const int mrow = mt * 16 + r0 + r;
                    if (mrow < 17) {
                        const int rg = s0 - 3 + mrow;
                        hsl[mrow][n] = (rg < 0) ? 0.f : acc[r] + bn_;
                    }
                }
            }
        }
    }
    __syncthreads();

    // ---- phase 1: conv (reads hsl; halo rows 0..2) ----
    {
        const float4 w = *(const float4*)&cw[i * 4];
        const float bi = cb[i];
        float* up = ut + (size_t)b * SS * II + i;
        float wm3 = hsl[0][i], wm2 = hsl[1][i], wm1 = hsl[2][i];
        for (int s = 0; s < TCH; ++s) {
            const float cur = hsl[s + 3][i];
            float a = fmaf(w.x, wm3, fmaf(w.y, wm2, fmaf(w.z, wm1, fmaf(w.w, cur, bi))));
            const float uv = siluf(a);
            up[(s0 + s) * II] = uv;
            uts[s][i] = uv;
            wm3 = wm2; wm2 = wm1; wm1 = cur;
        }
    }
    __syncthreads();

    // ---- phase 2: x_proj via MFMA (waves 0..2) — R10-validated ----
    {
        if (wv < 3) {
            const int srow = lrow;
            const short* wp = xws + ((size_t)(wv * 8) * 64 + lane) * 8;
            f32x4 acc = (f32x4){0.f, 0.f, 0.f, 0.f};
#pragma unroll
            for (int kt = 0; kt < 8; ++kt) {
                const float* up = &uts[0][0] + srow * (II + 4) + kt * 32 + lkg;
                const float4 a0 = *(const float4*)(up);
                const float4 a1 = *(const float4*)(up + 4);
                const bf16x8 af = cvt8v(a0, a1);
                const bf16x8 bf = *(const bf16x8*)(wp + (size_t)kt * 512);
                acc = __builtin_amdgcn_mfma_f32_16x16x32_bf16(af, bf, acc, 0, 0, 0);
            }
            const int col = wv * 16 + lrow;
            if (col < 40) {
#pragma unroll
                for (int r = 0; r < 4; ++r)
                    if (r0 + r < TCH) lsp[(r0 + r) * 40 + col] = acc[r];
            }
        }
    }
    __syncthreads();

    // sp -> global (scanB needs it)
    {
        float* spp = sp + ((size_t)b * SS + s0) * 40;
        for (int idx = i; idx < TCH * 40; idx += 256) spp[idx] = lsp[idx];
    }

    // ---- phase 3: scanA (exp2 with prescaled Ar2) ----
    float dw[8];
    {
        const float4 w0 = *(const float4*)&dtw[i * 8];
        const float4 w1 = *(const float4*)&dtw[i * 8 + 4];
        dw[0]=w0.x; dw[1]=w0.y; dw[2]=w0.z; dw[3]=w0.w;
        dw[4]=w1.x; dw[5]=w1.y; dw[6]=w1.z; dw[7]=w1.w;
    }
    const float bdt = dtb[i];
    float Ar2[NN];
#pragma unroll
    for (int n = 0; n < NN; ++n) Ar2[n] = -LOG2E * __expf(A_log[i * NN + n]);

    float st[NN];
#pragma unroll
    for (int n = 0; n < NN; ++n) st[n] = 0.f;
    float dtsum = 0.f;

    for (int s = 0; s < TCH; ++s) {
        const float uv = uts[s][i];
        const float* r = &lsp[s * 40];
        const float p0 = fmaf(r[1], dw[1], r[0] * dw[0]);
        const float p1 = fmaf(r[3], dw[3], r[2] * dw[2]);
        const float p2 = fmaf(r[5], dw[5], r[4] * dw[4]);
        const float p3 = fmaf(r[7], dw[7], r[6] * dw[6]);
        const float dtv = softplusf(bdt + (p0 + p1) + (p2 + p3));
        const float du = dtv * uv;
        dtsum += dtv;
#pragma unroll
        for (int n = 0; n < NN; ++n) {
            const float a = fexp2(dtv * Ar2[n]);
            st[n] = fmaf(a, st[n], du * r[8 + n]);
        }
    }
    dtsum_g[((size_t)b * NCH + ch) * II + i] = dtsum;
    float* qp = q + (((size_t)b * NCH + ch) * NN) * II + i;
#pragma unroll
    for (int n = 0; n < NN; ++n) qp[n * II] = st[n];
}

// ---------------------------------------------------------------------------
// Scan pass B + gate-GEMM + out_proj (R14/R16/R17-validated structure).
// R20: merged combine uses the closed form q_init[ch] = sum_c exp2(Ar2*S_c)
// * q_c with suffix sums S_c = sum ds[c+1..ch-1] — all loads independent
// (the R19 serial fma/load chain is gone).  Compile-time unrolled, uniform
// branch on c<ch (no scratch).
// ---------------------------------------------------------------------------
#define YLD 296   // ygl row stride (592B, 16B-aligned; 2-way bank alias, free)
__global__ __launch_bounds__(256)
void scanB_kernel(const float* __restrict__ ut, const float* __restrict__ sp,
                  const float* __restrict__ qloc, const float* __restrict__ dtsum_g,
                  const short* __restrict__ inws,
                  const short* __restrict__ outws, const short* __restrict__ hn,
                  const float* __restrict__ inb, const float* __restrict__ outb,
                  const float* __restrict__ dtw, const float* __restrict__ dtb,
                  const float* __restrict__ A_log, const float* __restrict__ Dp,
                  float* __restrict__ h)
{
    __shared__ float gsl[TCH][II + 4];
    __shared__ float lsp[TCH * 40];
    __shared__ __align__(16) short ygl[16 * YLD];
    const int b = blockIdx.x;
    const int ch = blockIdx.y;
    const int i = threadIdx.x;
    const int s0 = ch * TCH;
    const int lane = i & 63;
    const int wv = i >> 6;
    const int lrow = lane & 15;
    const int lkg = (lane >> 4) * 8;
    const int r0 = (lane >> 4) * 4;

    // ---- issue scan-loop ut loads up front — R16-validated ----
    const float* utp = ut + ((size_t)b * SS + s0) * II + i;
    float uvr[TCH];
#pragma unroll
    for (int s = 0; s < TCH; ++s) uvr[s] = utp[s * II];

    // Ar2 (needed for the merged combine)
    float Ar2[NN];
#pragma unroll
    for (int n = 0; n < NN; ++n) Ar2[n] = -LOG2E * __expf(A_log[i * NN + n]);

    // ---- merged combine (closed form, independent terms) ----
    float st[NN];
#pragma unroll
    for (int n = 0; n < NN; ++n) st[n] = 0.f;
    {
        const float* dsb = dtsum_g + ((size_t)b * NCH) * II + i;
        const float* qb  = qloc + (((size_t)b * NCH) * NN) * II + i;
        float dsv[NCH - 1];
#pragma unroll
        for (int c = 0; c < NCH - 1; ++c)
            dsv[c] = (c < ch) ? dsb[(size_t)c * II] : 0.f;
        // suffix sums: S_c = ds[c+1] + ... + ds[ch-1]
        float sc_[NCH - 1];
        {
            float S = 0.f;
#pragma unroll
            for (int c = NCH - 2; c >= 0; --c) {
                sc_[c] = S;
                if (c < ch) S += dsv[c];
            }
            // note: for c >= ch, sc_[c] unused
        }
#pragma unroll
        for (int c = 0; c < NCH - 1; ++c) {
            if (c < ch) {
                const float* qc = qb + (size_t)c * NN * II;
#pragma unroll
                for (int n = 0; n < NN; ++n)
                    st[n] = fmaf(fexp2(Ar2[n] * sc_[c]), qc[(size_t)n * II], st[n]);
            }
        }
    }

    // zero ygl rows 14,15 (A-rows beyond TCH)
    ygl[14 * YLD + i] = 0; ygl[15 * YLD + i] = 0;

    // ---- gate tile via MFMA (14 rows x 256 cols, K=128) — R13-validated ----
    {
        const short* hnb = hn + (size_t)b * SS * DM;
        const bool va = (lrow < TCH);
        const int rga = s0 + lrow;
        bf16x8 af[4];
#pragma unroll
        for (int kt = 0; kt < 4; ++kt) {
            if (va) af[kt] = *(const bf16x8*)(hnb + (size_t)rga * DM + kt * 32 + lkg);
            else { bf16x8 z = {0,0,0,0,0,0,0,0}; af[kt] = z; }
        }
#pragma unroll
        for (int j = 0; j < 4; ++j) {
            const int nt = 16 + wv * 4 + j;      // gate col-tiles 16..31
            f32x4 acc = (f32x4){0.f, 0.f, 0.f, 0.f};
#pragma unroll
            for (int kt = 0; kt < 4; ++kt) {
                const bf16x8 bf = *(const bf16x8*)(inws + ((size_t)(nt * 4 + kt) * 64 + lane) * 8);
                acc = __builtin_amdgcn_mfma_f32_16x16x32_bf16(af[kt], bf, acc, 0, 0, 0);
            }
            const int n = (nt - 16) * 16 + lrow;
            const float bn_ = inb[256 + n];
#pragma unroll
            for (int r = 0; r < 4; ++r)
                if (r0 + r < TCH) gsl[r0 + r][n] = acc[r] + bn_;
        }
    }

    // sp -> LDS
    {
        const float* spp = sp + ((size_t)b * SS + s0) * 40;
        for (int idx = i; idx < TCH * 40; idx += 256) lsp[idx] = spp[idx];
    }
    float dw[8];
    {
        const float4 w0 = *(const float4*)&dtw[i * 8];
        const float4 w1 = *(const float4*)&dtw[i * 8 + 4];
        dw[0]=w0.x; dw[1]=w0.y; dw[2]=w0.z; dw[3]=w0.w;
        dw[4]=w1.x; dw[5]=w1.y; dw[6]=w1.z; dw[7]=w1.w;
    }
    const float bdt = dtb[i];
    const float Dv = Dp[i];
    __syncthreads();

    for (int s = 0; s < TCH; ++s) {
        const float uv = uvr[s];
        const float* r = &lsp[s * 40];
        const float p0 = fmaf(r[1], dw[1], r[0] * dw[0]);
        const float p1 = fmaf(r[3], dw[3], r[2] * dw[2]);
        const float p2 = fmaf(r[5], dw[5], r[4] * dw[4]);
        const float p3 = fmaf(r[7], dw[7], r[6] * dw[6]);
        const float dtv = softplusf(bdt + (p0 + p1) + (p2 + p3));
        const float du = dtv * uv;
        float y0 = 0.f, y1 = 0.f, y2 = 0.f, y3 = 0.f;
#pragma unroll
        for (int n = 0; n < NN; n += 4) {
            const float a0 = fexp2(dtv * Ar2[n + 0]);
            const float a1 = fexp2(dtv * Ar2[n + 1]);
            const float a2 = fexp2(dtv * Ar2[n + 2]);
            const float a3 = fexp2(dtv * Ar2[n + 3]);
            st[n + 0] = fmaf(a0, st[n + 0], du * r[8 + n + 0]);
            st[n + 1] = fmaf(a1, st[n + 1], du * r[8 + n + 1]);
            st[n + 2] = fmaf(a2, st[n + 2], du * r[8 + n + 2]);
            st[n + 3] = fmaf(a3, st[n + 3], du * r[8 + n + 3]);
            y0 = fmaf(st[n + 0], r[24 + n + 0], y0);
            y1 = fmaf(st[n + 1], r[24 + n + 1], y1);
            y2 = fmaf(st[n + 2], r[24 + n + 2], y2);
            y3 = fmaf(st[n + 3], r[24 + n + 3], y3);
        }
        const float yv = (y0 + y1) + (y2 + y3) + uv * Dv;
        ygl[s * YLD + i] = f2bf(yv * siluf(gsl[s][i]));
    }
    __syncthreads();   // ygl complete

    // ---- out_proj via MFMA: h[s0..s0+13][0..127] += ygl @ out_w^T + b ----
    {
        bf16x8 af[8];
#pragma unroll
        for (int kt = 0; kt < 8; ++kt)
            af[kt] = *(const bf16x8*)&ygl[lrow * YLD + kt * 32 + lkg];
#pragma unroll
        for (int j = 0; j < 2; ++j) {
            const int nt = wv * 2 + j;           // 0..7 (128 h cols)
            f32x4 acc = (f32x4){0.f, 0.f, 0.f, 0.f};
#pragma unroll
            for (int kt = 0; kt < 8; ++kt) {
                const bf16x8 bf = *(const bf16x8*)(outws + ((size_t)(nt * 8 + kt) * 64 + lane) * 8);
                acc = __builtin_amdgcn_mfma_f32_16x16x32_bf16(af[kt], bf, acc, 0, 0, 0);
            }
            const int col = nt * 16 + lrow;
            const float bo = outb[col];
#pragma unroll
            for (int r = 0; r < 4; ++r) {
                const int srow = r0 + r;
                if (srow < TCH) {
                    float* hp = &h[((size_t)b * SS + s0 + srow) * DM + col];
                    *hp += acc[r] + bo;
                }
            }
        }
    }
}

// ---------------------------------------------------------------------------
// Final head: rmsnorm(h[b,S-1,:]) -> layernorm -> fc -> out[b,p]
// ---------------------------------------------------------------------------
__global__ __launch_bounds__(64)
void final_kernel(const float* __restrict__ h, const float* __restrict__ fnw,
                  const float* __restrict__ lnw, const float* __restrict__ lnb,
                  const float* __restrict__ fcw, const float* __restrict__ fcb,
                  float* __restrict__ out)
{
    __shared__ float last[DM];
    const int b = blockIdx.x;
    const int lane = threadIdx.x;
    const float* hp = &h[((size_t)b * SS + (SS - 1)) * DM];
    const float2 v = *(const float2*)&hp[lane * 2];
    const float ss = wave_sum(v.x * v.x + v.y * v.y);
    const float sc = rsqrtf(ss * (1.f / DM) + 1e-5f);
    const float2 fw = *(const float2*)&fnw[lane * 2];
    const float t0 = v.x * sc * fw.x, t1 = v.y * sc * fw.y;
    const float m = wave_sum(t0 + t1) * (1.f / DM);
    const float d0 = t0 - m, d1 = t1 - m;
    const float var = wave_sum(d0 * d0 + d1 * d1) * (1.f / DM);
    const float iv = rsqrtf(var + 1e-5f);
    const float2 lw = *(const float2*)&lnw[lane * 2];
    const float2 lb = *(const float2*)&lnb[lane * 2];
    last[lane * 2]     = d0 * iv * lw.x + lb.x;
    last[lane * 2 + 1] = d1 * iv * lw.y + lb.y;
    __syncthreads();
    if (lane < PP) {
        float a = fcb[lane];
#pragma unroll 8
        for (int d = 0; d < DM; ++d) a = fmaf(last[d], fcw[lane * DM + d], a);
        out[b * PP + lane] = a;
    }
}

// ---------------------------------------------------------------------------
extern "C" void kernel_launch(void* const* d_in, const int* in_sizes, int n_in,
                              void* d_out, int out_size, void* d_ws, size_t ws_size,
                              hipStream_t stream)
{
    (void)in_sizes; (void)n_in; (void)out_size; (void)ws_size;
    const float* x_load = (const float*)d_in[0];
    const float* x_img  = (const float*)d_in[1];
    const float* x_text = (const float*)d_in[2];
    const float* Wl     = (const float*)d_in[3];
    const float* Wi     = (const float*)d_in[4];
    const float* Wt     = (const float*)d_in[5];
    const float* b_fuse = (const float*)d_in[6];
    const float* mnorm_w= (const float*)d_in[7];
    const float* in_w   = (const float*)d_in[8];
    const float* in_b   = (const float*)d_in[9];
    const float* conv_w = (const float*)d_in[10];
    const float* conv_b = (const float*)d_in[11];
    const float* xp_w   = (const float*)d_in[12];
    const float* dt_w   = (const float*)d_in[13];
    const float* dt_b   = (const float*)d_in[14];
    const float* A_log  = (const float*)d_in[15];
    const float* Dp     = (const float*)d_in[16];
    const float* out_w  = (const float*)d_in[17];
    const float* out_b  = (const float*)d_in[18];
    const float* fnorm_w= (const float*)d_in[19];
    const float* ln_w   = (const float*)d_in[20];
    const float* ln_b   = (const float*)d_in[21];
    const float* fc_w   = (const float*)d_in[22];
    const float* fc_b   = (const float*)d_in[23];

    float* ws  = (float*)d_ws;
    float* h     = ws;                               // [21504][128]
    float* ut    = h  + (size_t)MROWS * DM;          // [21504][256]
    float* sp    = ut + (size_t)MROWS * II;          // [21504][40]
    float* q     = sp + (size_t)MROWS * 40;          // [B][NCH][NN][II]
    float* dtsum = q  + (size_t)BB * NCH * NN * II;  // [B][NCH][II]
    short* pool  = (short*)(dtsum + (size_t)BB * NCH * II); // frag pool
    short* hn    = pool + (size_t)FR_TOT * 512;      // [21504][128] bf16

    // one-shot weight swizzle (xp_w + in_w + out_w)
    cvtw_kernel<<<(FR_TOT * 64 + 255) / 256, 256, 0, stream>>>(
        xp_w, in_w, out_w, pool);

    // --- feature fusion (text + img + rank-1 load + bias) ---
    gemm_mfma<false><<<dim3(MROWS / 32, 2), 256, 0, stream>>>(
        x_text, nullptr, Wt, 768, x_img, Wi, 64, b_fuse, x_load, Wl,
        h, DM);

    for (int l = 0; l < LL; ++l) {
        const short* xws   = pool + (size_t)l * XPF * 512;
        const short* inws  = pool + (size_t)(LL * XPF + l * INF) * 512;
        const short* outws = pool + (size_t)(LL * (XPF + INF) + l * OUTF) * 512;
        // rmsnorm'd bf16 A-panel
        hn_kernel<<<MROWS / 4, 256, 0, stream>>>(h, mnorm_w + l * DM, hn);
        // hs-GEMM + conv + x_proj + scanA
        fusedA_kernel<<<dim3(BB, NCH), 256, 0, stream>>>(
            hn, conv_w + l * II * KK, conv_b + l * II, inws, xws,
            in_b + (size_t)l * 2 * II,
            dt_w + l * II * RR, dt_b + l * II, A_log + l * II * NN,
            ut, sp, dtsum, q);
        // gate-GEMM + scanB (closed-form combine) + out_proj (h += ...)
        scanB_kernel<<<dim3(BB, NCH), 256, 0, stream>>>(
            ut, sp, q, dtsum, inws, outws, hn,
            in_b + (size_t)l * 2 * II, out_b + l * DM,
            dt_w + l * II * RR, dt_b + l * II,
            A_log + l * II * NN, Dp + l * II, h);
    }

    final_kernel<<<BB, 64, 0, stream>>>(h, fnorm_w, ln_w, ln_b, fc_w, fc_b,
                                        (float*)d_out);
}

// Round 21
// 181.720 us; speedup vs baseline: 1.0428x; 1.0428x over previous
//
#include <hip/hip_runtime.h>
#include <hip/hip_bf16.h>

// Problem constants
#define BB   128
#define SS   168
#define DM   128
#define LL   2
#define II   256
#define NN   16
#define RR   8
#define KK   4
#define PP   24
#define MROWS (BB*SS)   // 21504
#define NCH  12         // scan chunks
#define TCH  14         // SS / NCH (fits one MFMA M=16 tile)
#define LOG2E 1.4426950408889634f

// bf16 fragment pool: xp_w (24/layer) + in_w (128/layer) + out_w (64/layer)
#define XPF  24
#define INF  128
#define OUTF 64
#define FR_TOT (LL*(XPF+INF+OUTF))   // 432

typedef __attribute__((ext_vector_type(8))) short bf16x8;
typedef __attribute__((ext_vector_type(4))) short bf16x4;
typedef __attribute__((ext_vector_type(4))) float f32x4;

__device__ __forceinline__ float wave_sum(float x) {
#pragma unroll
    for (int off = 32; off > 0; off >>= 1) x += __shfl_xor(x, off);
    return x;
}
__device__ __forceinline__ float fexp2(float x) {   // v_exp_f32 (2^x)
    return __builtin_amdgcn_exp2f(x);
}
__device__ __forceinline__ float siluf(float x) {   // fast: rcp + exp2
    return x * __builtin_amdgcn_rcpf(1.f + fexp2(-LOG2E * x));
}
__device__ __forceinline__ float softplusf(float x) {
    return (x > 20.f) ? x : __logf(1.f + __expf(x));
}
__device__ __forceinline__ short f2bf(float x) {   // RNE f32 -> bf16
    unsigned u = __builtin_bit_cast(unsigned, x);
    u = (u + 0x7FFFu + ((u >> 16) & 1u)) >> 16;
    return (short)u;
}
// HW packed f32->bf16 (RNE): 4 floats -> bf16x4 (R20-validated)
__device__ __forceinline__ bf16x4 cvt4v(float4 a) {
    unsigned u0, u1;
    asm("v_cvt_pk_bf16_f32 %0, %1, %2" : "=v"(u0) : "v"(a.x), "v"(a.y));
    asm("v_cvt_pk_bf16_f32 %0, %1, %2" : "=v"(u1) : "v"(a.z), "v"(a.w));
    union { unsigned u[2]; bf16x4 v; } r;
    r.u[0] = u0; r.u[1] = u1;
    return r.v;
}
// HW packed f32->bf16 (RNE): 8 floats -> bf16x8 (validated R2/R5/R10)
__device__ __forceinline__ bf16x8 cvt8v(float4 a, float4 b) {
    unsigned u0, u1, u2, u3;
    asm("v_cvt_pk_bf16_f32 %0, %1, %2" : "=v"(u0) : "v"(a.x), "v"(a.y));
    asm("v_cvt_pk_bf16_f32 %0, %1, %2" : "=v"(u1) : "v"(a.z), "v"(a.w));
    asm("v_cvt_pk_bf16_f32 %0, %1, %2" : "=v"(u2) : "v"(b.x), "v"(b.y));
    asm("v_cvt_pk_bf16_f32 %0, %1, %2" : "=v"(u3) : "v"(b.z), "v"(b.w));
    union { unsigned u[4]; bf16x8 v; } r;
    r.u[0] = u0; r.u[1] = u1; r.u[2] = u2; r.u[3] = u3;
    return r.v;
}

// ---------------------------------------------------------------------------
// hn = bf16(h * rsqrt(mean(h^2)+eps) * mnw) — rowscale via wave_sum
// (R12-validated). One wave per row.
// ---------------------------------------------------------------------------
__global__ __launch_bounds__(256)
void hn_kernel(const float* __restrict__ h, const float* __restrict__ mnw,
               short* __restrict__ hn)
{
    const int row  = blockIdx.x * 4 + (threadIdx.x >> 6);
    const int lane = threadIdx.x & 63;
    const float2 v = *(const float2*)&h[(size_t)row * DM + lane * 2];
    const float ss = wave_sum(v.x * v.x + v.y * v.y);
    const float rsv = rsqrtf(ss * (1.f / DM) + 1e-5f);
    const float2 w = *(const float2*)&mnw[lane * 2];
    short2 o;
    o.x = f2bf(v.x * rsv * w.x);
    o.y = f2bf(v.y * rsv * w.y);
    *(short2*)&hn[(size_t)row * DM + lane * 2] = o;
}

// ---------------------------------------------------------------------------
// One-shot weight swizzle to MFMA B-fragment order (R10/R13-validated).
// Pool: [xp l0|l1 (24 ea)][inw l0|l1 (128 ea)][outw l0|l1 (64 ea)].
// ---------------------------------------------------------------------------
__global__ __launch_bounds__(256)
void cvtw_kernel(const float* __restrict__ xw, const float* __restrict__ inw,
                 const float* __restrict__ outw, short* __restrict__ dst)
{
    const int tid = blockIdx.x * 256 + threadIdx.x;
    if (tid >= FR_TOT * 64) return;
    const int lane = tid & 63;
    const int fg = tid >> 6;
    float4 v0 = {0.f, 0.f, 0.f, 0.f}, v1 = {0.f, 0.f, 0.f, 0.f};
    if (fg < LL * XPF) {
        const int l = fg / XPF, f = fg % XPF;
        const int nt = f >> 3, kt = f & 7;
        const int row = nt * 16 + (lane & 15);
        const int kc = kt * 32 + (lane >> 4) * 8;
        if (row < 40) {
            const float* s = xw + ((size_t)l * 40 + row) * II + kc;
            v0 = *(const float4*)s;
            v1 = *(const float4*)(s + 4);
        }
    } else if (fg < LL * (XPF + INF)) {
        const int g = fg - LL * XPF;
        const int l = g / INF, fi = g % INF;
        const int nt = fi >> 2, kt = fi & 3;
        const int row = nt * 16 + (lane & 15);          // 0..511
        const int kc = kt * 32 + (lane >> 4) * 8;       // 0..127
        const float* s = inw + ((size_t)l * 2 * II + row) * DM + kc;
        v0 = *(const float4*)s;
        v1 = *(const float4*)(s + 4);
    } else {
        const int g = fg - LL * (XPF + INF);
        const int l = g / OUTF, fo = g % OUTF;
        const int nt = fo >> 3, kt = fo & 7;            // nt 0..7, kt 0..7
        const int row = nt * 16 + (lane & 15);          // 0..127
        const int kc = kt * 32 + (lane >> 4) * 8;       // 0..255
        const float* s = outw + ((size_t)l * DM + row) * II + kc;
        v0 = *(const float4*)s;
        v1 = *(const float4*)(s + 4);
    }
    *(bf16x8*)(dst + ((size_t)tid) * 8) = cvt8v(v0, v1);
}

// ---------------------------------------------------------------------------
// bf16-MFMA GEMM — R11-exact schedule (fusion only).  R20-validated HW
// v_cvt_pk pack (RNE-identical) — fusion left the top-5 with this change.
// ---------------------------------------------------------------------------
#define LDT 40
template<bool ACCUM>
__global__ __launch_bounds__(256)
void gemm_mfma(const float* __restrict__ A, const short* __restrict__ Abf,
               const float* __restrict__ W, int K,
               const float* __restrict__ A2, const float* __restrict__ W2, int K2,
               const float* __restrict__ bias,
               const float* __restrict__ r1x, const float* __restrict__ r1w,
               float* __restrict__ C, int ldc)
{
    __shared__ __align__(16) short Asl[32 * LDT];
    __shared__ __align__(16) short Bsl[64 * LDT];
    const int bm = blockIdx.x * 32;
    const int bn = blockIdx.y * 64;
    const int t  = threadIdx.x;
    const int lane = t & 63;
    const int wave = t >> 6;
    const int wr = wave >> 1, wc = wave & 1;
    const int lrow = lane & 15;
    const int lk   = (lane >> 4) * 8;

    f32x4 acc[2];
    acc[0] = (f32x4){0.f, 0.f, 0.f, 0.f};
    acc[1] = (f32x4){0.f, 0.f, 0.f, 0.f};

    const int arow = t >> 3, ak = (t & 7) * 4;    // A: 32 rows x 32 k
    const int brow = t >> 2, bk = (t & 3) * 8;    // B: 64 rows x 32 k

    float av[4], bv[8];
    bf16x4 avb;

#pragma unroll 1
    for (int pass = 0; pass < 2; ++pass) {
        const bool useBf = (pass == 0) && (Abf != nullptr);
        const float* Ap = pass ? A2 : A;
        if (!Ap && !useBf) continue;
        const float* Wp = pass ? W2 : W;
        const int    Kp = pass ? K2 : K;
        const short* abptr = useBf ? Abf + (size_t)(bm + arow) * Kp + ak : nullptr;
        const float* aptr  = useBf ? nullptr : Ap + (size_t)(bm + arow) * Kp + ak;
        const float* bptr = Wp + (size_t)(bn + brow) * Kp + bk;

        // prologue load (k0 = 0)
        if (useBf) avb = *(const bf16x4*)(abptr);
        else       *(float4*)&av[0] = *(const float4*)(aptr);
        *(float4*)&bv[0] = *(const float4*)(bptr);
        *(float4*)&bv[4] = *(const float4*)(bptr + 4);

#pragma unroll 1
        for (int k0 = 0; k0 < Kp; k0 += 32) {
            __syncthreads();   // previous iteration's LDS reads done
            if (useBf) *(bf16x4*)&Asl[arow * LDT + ak] = avb;
            else       *(bf16x4*)&Asl[arow * LDT + ak] = cvt4v(*(const float4*)&av[0]);
            *(bf16x8*)&Bsl[brow * LDT + bk] =
                cvt8v(*(const float4*)&bv[0], *(const float4*)&bv[4]);
            __syncthreads();
            const int kn = k0 + 32;
            if (kn < Kp) {   // prefetch next tile while MFMA runs
                if (useBf) avb = *(const bf16x4*)(abptr + kn);
                else       *(float4*)&av[0] = *(const float4*)(aptr + kn);
                *(float4*)&bv[0] = *(const float4*)(bptr + kn);
                *(float4*)&bv[4] = *(const float4*)(bptr + kn + 4);
            }
            const bf16x8 af = *(const bf16x8*)&Asl[(wr * 16 + lrow) * LDT + lk];
            bf16x8 bfr[2];
#pragma unroll
            for (int ni = 0; ni < 2; ++ni)
                bfr[ni] = *(const bf16x8*)&Bsl[(wc * 32 + ni * 16 + lrow) * LDT + lk];
#pragma unroll
            for (int ni = 0; ni < 2; ++ni)
                acc[ni] = __builtin_amdgcn_mfma_f32_16x16x32_bf16(af, bfr[ni], acc[ni], 0, 0, 0);
        }
    }

    // epilogue
#pragma unroll
    for (int r = 0; r < 4; ++r) {
        const int row = bm + wr * 16 + (lane >> 4) * 4 + r;
        const float xl = r1x ? r1x[row] : 0.f;
#pragma unroll
        for (int ni = 0; ni < 2; ++ni) {
            const int col = bn + wc * 32 + ni * 16 + lrow;
            float v = acc[ni][r];
            if (bias) v += bias[col];
            if (r1x)  v += xl * r1w[col];
            float* cp = &C[(size_t)row * ldc + col];
            if (ACCUM) v += *cp;
            *cp = v;
        }
    }
}

// ---------------------------------------------------------------------------
// Fused hs-GEMM + conv + x_proj(MFMA) + scanA per (b, chunk) — R13/R14/R17
// validated (exp2 with prescaled Ar2).
// ---------------------------------------------------------------------------
__global__ __launch_bounds__(256)
void fusedA_kernel(const short* __restrict__ hn, const float* __restrict__ cw,
                   const float* __restrict__ cb, const short* __restrict__ inws,
                   const short* __restrict__ xws, const float* __restrict__ inb,
                   const float* __restrict__ dtw, const float* __restrict__ dtb,
                   const float* __restrict__ A_log,
                   float* __restrict__ ut, float* __restrict__ sp,
                   float* __restrict__ dtsum_g, float* __restrict__ q)
{
    __shared__ float hsl[17][II + 4];    // hs tile incl. 3 halo rows
    __shared__ float uts[TCH][II + 4];   // 14 x 260
    __shared__ float lsp[TCH * 40];
    const int b = blockIdx.x;
    const int ch = blockIdx.y;
    const int i = threadIdx.x;
    const int s0 = ch * TCH;
    const int lane = i & 63;
    const int wv = i >> 6;
    const int lrow = lane & 15;
    const int lkg = (lane >> 4) * 8;
    const int r0 = (lane >> 4) * 4;

    // ---- phase 0: hs tile via MFMA (17 rows x 256 cols, K=128) ----
    {
        const short* hnb = hn + (size_t)b * SS * DM;
#pragma unroll
        for (int mt = 0; mt < 2; ++mt) {
            const int ma = mt * 16 + lrow;       // A row within tile
            const int rga = s0 - 3 + ma;
            const bool va = (ma < 17) && (rga >= 0);
            bf16x8 af[4];
#pragma unroll
            for (int kt = 0; kt < 4; ++kt) {
                if (va) af[kt] = *(const bf16x8*)(hnb + (size_t)rga * DM + kt * 32 + lkg);
                else { bf16x8 z = {0,0,0,0,0,0,0,0}; af[kt] = z; }
            }
#pragma unroll
            for (int j = 0; j < 4; ++j) {
                const int nt = wv * 4 + j;       // 0..15 (hs cols)
                f32x4 acc = (f32x4){0.f, 0.f, 0.f, 0.f};
#pragma unroll
                for (int kt = 0; kt < 4; ++kt) {
                    const bf16x8 bf = *(const bf16x8*)(inws + ((size_t)(nt * 4 + kt) * 64 + lane) * 8);
                    acc = __builtin_amdgcn_mfma_f32_16x16x32_bf16(af[kt], bf, acc, 0, 0, 0);
                }
                const int n = nt * 16 + lrow;
                const float bn_ = inb[n];
#pragma unroll
                for (int r = 0; r < 4; ++r) {
                    const int mrow = mt * 16 + r0 + r;
                    if (mrow < 17) {
                        const int rg = s0 - 3 + mrow;
                        hsl[mrow][n] = (rg < 0) ? 0.f : acc[r] + bn_;
                    }
                }
            }
        }
    }
    __syncthreads();

    // ---- phase 1: conv (reads hsl; halo rows 0..2) ----
    {
        const float4 w = *(const float4*)&cw[i * 4];
        const float bi = cb[i];
        float* up = ut + (size_t)b * SS * II + i;
        float wm3 = hsl[0][i], wm2 = hsl[1][i], wm1 = hsl[2][i];
        for (int s = 0; s < TCH; ++s) {
            const float cur = hsl[s + 3][i];
            float a = fmaf(w.x, wm3, fmaf(w.y, wm2, fmaf(w.z, wm1, fmaf(w.w, cur, bi))));
            const float uv = siluf(a);
            up[(s0 + s) * II] = uv;
            uts[s][i] = uv;
            wm3 = wm2; wm2 = wm1; wm1 = cur;
        }
    }
    __syncthreads();

    // ---- phase 2: x_proj via MFMA (waves 0..2) — R10-validated ----
    {
        if (wv < 3) {
            const int srow = lrow;
            const short* wp = xws + ((size_t)(wv * 8) * 64 + lane) * 8;
            f32x4 acc = (f32x4){0.f, 0.f, 0.f, 0.f};
#pragma unroll
            for (int kt = 0; kt < 8; ++kt) {
                const float* up = &uts[0][0] + srow * (II + 4) + kt * 32 + lkg;
                const float4 a0 = *(const float4*)(up);
                const float4 a1 = *(const float4*)(up + 4);
                const bf16x8 af = cvt8v(a0, a1);
                const bf16x8 bf = *(const bf16x8*)(wp + (size_t)kt * 512);
                acc = __builtin_amdgcn_mfma_f32_16x16x32_bf16(af, bf, acc, 0, 0, 0);
            }
            const int col = wv * 16 + lrow;
            if (col < 40) {
#pragma unroll
                for (int r = 0; r < 4; ++r)
                    if (r0 + r < TCH) lsp[(r0 + r) * 40 + col] = acc[r];
            }
        }
    }
    __syncthreads();

    // sp -> global (scanB needs it)
    {
        float* spp = sp + ((size_t)b * SS + s0) * 40;
        for (int idx = i; idx < TCH * 40; idx += 256) spp[idx] = lsp[idx];
    }

    // ---- phase 3: scanA (exp2 with prescaled Ar2) ----
    float dw[8];
    {
        const float4 w0 = *(const float4*)&dtw[i * 8];
        const float4 w1 = *(const float4*)&dtw[i * 8 + 4];
        dw[0]=w0.x; dw[1]=w0.y; dw[2]=w0.z; dw[3]=w0.w;
        dw[4]=w1.x; dw[5]=w1.y; dw[6]=w1.z; dw[7]=w1.w;
    }
    const float bdt = dtb[i];
    float Ar2[NN];
#pragma unroll
    for (int n = 0; n < NN; ++n) Ar2[n] = -LOG2E * __expf(A_log[i * NN + n]);

    float st[NN];
#pragma unroll
    for (int n = 0; n < NN; ++n) st[n] = 0.f;
    float dtsum = 0.f;

    for (int s = 0; s < TCH; ++s) {
        const float uv = uts[s][i];
        const float* r = &lsp[s * 40];
        const float p0 = fmaf(r[1], dw[1], r[0] * dw[0]);
        const float p1 = fmaf(r[3], dw[3], r[2] * dw[2]);
        const float p2 = fmaf(r[5], dw[5], r[4] * dw[4]);
        const float p3 = fmaf(r[7], dw[7], r[6] * dw[6]);
        const float dtv = softplusf(bdt + (p0 + p1) + (p2 + p3));
        const float du = dtv * uv;
        dtsum += dtv;
#pragma unroll
        for (int n = 0; n < NN; ++n) {
            const float a = fexp2(dtv * Ar2[n]);
            st[n] = fmaf(a, st[n], du * r[8 + n]);
        }
    }
    dtsum_g[((size_t)b * NCH + ch) * II + i] = dtsum;
    float* qp = q + (((size_t)b * NCH + ch) * NN) * II + i;
#pragma unroll
    for (int n = 0; n < NN; ++n) qp[n * II] = st[n];
}

// ---------------------------------------------------------------------------
// Scan pass B + gate-GEMM + out_proj (R14/R16/R17-validated structure).
// R19-exact merged combine (serial fma recurrence — R20's closed form
// REGRESSED, reverted): st init via c-ascending cur = fma(Pv, cur, qv).
// ---------------------------------------------------------------------------
#define YLD 296   // ygl row stride (592B, 16B-aligned; 2-way bank alias, free)
__global__ __launch_bounds__(256)
void scanB_kernel(const float* __restrict__ ut, const float* __restrict__ sp,
                  const float* __restrict__ qloc, const float* __restrict__ dtsum_g,
                  const short* __restrict__ inws,
                  const short* __restrict__ outws, const short* __restrict__ hn,
                  const float* __restrict__ inb, const float* __restrict__ outb,
                  const float* __restrict__ dtw, const float* __restrict__ dtb,
                  const float* __restrict__ A_log, const float* __restrict__ Dp,
                  float* __restrict__ h)
{
    __shared__ float gsl[TCH][II + 4];
    __shared__ float lsp[TCH * 40];
    __shared__ __align__(16) short ygl[16 * YLD];
    const int b = blockIdx.x;
    const int ch = blockIdx.y;
    const int i = threadIdx.x;
    const int s0 = ch * TCH;
    const int lane = i & 63;
    const int wv = i >> 6;
    const int lrow = lane & 15;
    const int lkg = (lane >> 4) * 8;
    const int r0 = (lane >> 4) * 4;

    // ---- issue scan-loop ut loads up front — R16-validated ----
    const float* utp = ut + ((size_t)b * SS + s0) * II + i;
    float uvr[TCH];
#pragma unroll
    for (int s = 0; s < TCH; ++s) uvr[s] = utp[s * II];

    // Ar2 (needed for the merged combine recurrence)
    float Ar2[NN];
#pragma unroll
    for (int n = 0; n < NN; ++n) Ar2[n] = -LOG2E * __expf(A_log[i * NN + n]);

    // ---- merged combine: st = q_init[ch] via the exact combine recurrence
    //      (c = 0..ch-1 ascending, cur = fma(Pv, cur, qv)) — R19-validated ----
    float st[NN];
#pragma unroll
    for (int n = 0; n < NN; ++n) st[n] = 0.f;
    {
        const float* dsb = dtsum_g + ((size_t)b * NCH) * II + i;
        const float* qb  = qloc + (((size_t)b * NCH) * NN) * II + i;
        for (int c = 0; c < ch; ++c) {
            const float dsc = dsb[(size_t)c * II];
            const float* qc = qb + (size_t)c * NN * II;
#pragma unroll
            for (int n = 0; n < NN; ++n)
                st[n] = fmaf(fexp2(Ar2[n] * dsc), st[n], qc[(size_t)n * II]);
        }
    }

    // zero ygl rows 14,15 (A-rows beyond TCH)
    ygl[14 * YLD + i] = 0; ygl[15 * YLD + i] = 0;

    // ---- gate tile via MFMA (14 rows x 256 cols, K=128) — R13-validated ----
    {
        const short* hnb = hn + (size_t)b * SS * DM;
        const bool va = (lrow < TCH);
        const int rga = s0 + lrow;
        bf16x8 af[4];
#pragma unroll
        for (int kt = 0; kt < 4; ++kt) {
            if (va) af[kt] = *(const bf16x8*)(hnb + (size_t)rga * DM + kt * 32 + lkg);
            else { bf16x8 z = {0,0,0,0,0,0,0,0}; af[kt] = z; }
        }
#pragma unroll
        for (int j = 0; j < 4; ++j) {
            const int nt = 16 + wv * 4 + j;      // gate col-tiles 16..31
            f32x4 acc = (f32x4){0.f, 0.f, 0.f, 0.f};
#pragma unroll
            for (int kt = 0; kt < 4; ++kt) {
                const bf16x8 bf = *(const bf16x8*)(inws + ((size_t)(nt * 4 + kt) * 64 + lane) * 8);
                acc = __builtin_amdgcn_mfma_f32_16x16x32_bf16(af[kt], bf, acc, 0, 0, 0);
            }
            const int n = (nt - 16) * 16 + lrow;
            const float bn_ = inb[256 + n];
#pragma unroll
            for (int r = 0; r < 4; ++r)
                if (r0 + r < TCH) gsl[r0 + r][n] = acc[r] + bn_;
        }
    }

    // sp -> LDS
    {
        const float* spp = sp + ((size_t)b * SS + s0) * 40;
        for (int idx = i; idx < TCH * 40; idx += 256) lsp[idx] = spp[idx];
    }
    float dw[8];
    {
        const float4 w0 = *(const float4*)&dtw[i * 8];
        const float4 w1 = *(const float4*)&dtw[i * 8 + 4];
        dw[0]=w0.x; dw[1]=w0.y; dw[2]=w0.z; dw[3]=w0.w;
        dw[4]=w1.x; dw[5]=w1.y; dw[6]=w1.z; dw[7]=w1.w;
    }
    const float bdt = dtb[i];
    const float Dv = Dp[i];
    __syncthreads();

    for (int s = 0; s < TCH; ++s) {
        const float uv = uvr[s];
        const float* r = &lsp[s * 40];
        const float p0 = fmaf(r[1], dw[1], r[0] * dw[0]);
        const float p1 = fmaf(r[3], dw[3], r[2] * dw[2]);
        const float p2 = fmaf(r[5], dw[5], r[4] * dw[4]);
        const float p3 = fmaf(r[7], dw[7], r[6] * dw[6]);
        const float dtv = softplusf(bdt + (p0 + p1) + (p2 + p3));
        const float du = dtv * uv;
        float y0 = 0.f, y1 = 0.f, y2 = 0.f, y3 = 0.f;
#pragma unroll
        for (int n = 0; n < NN; n += 4) {
            const float a0 = fexp2(dtv * Ar2[n + 0]);
            const float a1 = fexp2(dtv * Ar2[n + 1]);
            const float a2 = fexp2(dtv * Ar2[n + 2]);
            const float a3 = fexp2(dtv * Ar2[n + 3]);
            st[n + 0] = fmaf(a0, st[n + 0], du * r[8 + n + 0]);
            st[n + 1] = fmaf(a1, st[n + 1], du * r[8 + n + 1]);
            st[n + 2] = fmaf(a2, st[n + 2], du * r[8 + n + 2]);
            st[n + 3] = fmaf(a3, st[n + 3], du * r[8 + n + 3]);
            y0 = fmaf(st[n + 0], r[24 + n + 0], y0);
            y1 = fmaf(st[n + 1], r[24 + n + 1], y1);
            y2 = fmaf(st[n + 2], r[24 + n + 2], y2);
            y3 = fmaf(st[n + 3], r[24 + n + 3], y3);
        }
        const float yv = (y0 + y1) + (y2 + y3) + uv * Dv;
        ygl[s * YLD + i] = f2bf(yv * siluf(gsl[s][i]));
    }
    __syncthreads();   // ygl complete

    // ---- out_proj via MFMA: h[s0..s0+13][0..127] += ygl @ out_w^T + b ----
    {
        bf16x8 af[8];
#pragma unroll
        for (int kt = 0; kt < 8; ++kt)
            af[kt] = *(const bf16x8*)&ygl[lrow * YLD + kt * 32 + lkg];
#pragma unroll
        for (int j = 0; j < 2; ++j) {
            const int nt = wv * 2 + j;           // 0..7 (128 h cols)
            f32x4 acc = (f32x4){0.f, 0.f, 0.f, 0.f};
#pragma unroll
            for (int kt = 0; kt < 8; ++kt) {
                const bf16x8 bf = *(const bf16x8*)(outws + ((size_t)(nt * 8 + kt) * 64 + lane) * 8);
                acc = __builtin_amdgcn_mfma_f32_16x16x32_bf16(af[kt], bf, acc, 0, 0, 0);
            }
            const int col = nt * 16 + lrow;
            const float bo = outb[col];
#pragma unroll
            for (int r = 0; r < 4; ++r) {
                const int srow = r0 + r;
                if (srow < TCH) {
                    float* hp = &h[((size_t)b * SS + s0 + srow) * DM + col];
                    *hp += acc[r] + bo;
                }
            }
        }
    }
}

// ---------------------------------------------------------------------------
// Final head: rmsnorm(h[b,S-1,:]) -> layernorm -> fc -> out[b,p]
// ---------------------------------------------------------------------------
__global__ __launch_bounds__(64)
void final_kernel(const float* __restrict__ h, const float* __restrict__ fnw,
                  const float* __restrict__ lnw, const float* __restrict__ lnb,
                  const float* __restrict__ fcw, const float* __restrict__ fcb,
                  float* __restrict__ out)
{
    __shared__ float last[DM];
    const int b = blockIdx.x;
    const int lane = threadIdx.x;
    const float* hp = &h[((size_t)b * SS + (SS - 1)) * DM];
    const float2 v = *(const float2*)&hp[lane * 2];
    const float ss = wave_sum(v.x * v.x + v.y * v.y);
    const float sc = rsqrtf(ss * (1.f / DM) + 1e-5f);
    const float2 fw = *(const float2*)&fnw[lane * 2];
    const float t0 = v.x * sc * fw.x, t1 = v.y * sc * fw.y;
    const float m = wave_sum(t0 + t1) * (1.f / DM);
    const float d0 = t0 - m, d1 = t1 - m;
    const float var = wave_sum(d0 * d0 + d1 * d1) * (1.f / DM);
    const float iv = rsqrtf(var + 1e-5f);
    const float2 lw = *(const float2*)&lnw[lane * 2];
    const float2 lb = *(const float2*)&lnb[lane * 2];
    last[lane * 2]     = d0 * iv * lw.x + lb.x;
    last[lane * 2 + 1] = d1 * iv * lw.y + lb.y;
    __syncthreads();
    if (lane < PP) {
        float a = fcb[lane];
#pragma unroll 8
        for (int d = 0; d < DM; ++d) a = fmaf(last[d], fcw[lane * DM + d], a);
        out[b * PP + lane] = a;
    }
}

// ---------------------------------------------------------------------------
extern "C" void kernel_launch(void* const* d_in, const int* in_sizes, int n_in,
                              void* d_out, int out_size, void* d_ws, size_t ws_size,
                              hipStream_t stream)
{
    (void)in_sizes; (void)n_in; (void)out_size; (void)ws_size;
    const float* x_load = (const float*)d_in[0];
    const float* x_img  = (const float*)d_in[1];
    const float* x_text = (const float*)d_in[2];
    const float* Wl     = (const float*)d_in[3];
    const float* Wi     = (const float*)d_in[4];
    const float* Wt     = (const float*)d_in[5];
    const float* b_fuse = (const float*)d_in[6];
    const float* mnorm_w= (const float*)d_in[7];
    const float* in_w   = (const float*)d_in[8];
    const float* in_b   = (const float*)d_in[9];
    const float* conv_w = (const float*)d_in[10];
    const float* conv_b = (const float*)d_in[11];
    const float* xp_w   = (const float*)d_in[12];
    const float* dt_w   = (const float*)d_in[13];
    const float* dt_b   = (const float*)d_in[14];
    const float* A_log  = (const float*)d_in[15];
    const float* Dp     = (const float*)d_in[16];
    const float* out_w  = (const float*)d_in[17];
    const float* out_b  = (const float*)d_in[18];
    const float* fnorm_w= (const float*)d_in[19];
    const float* ln_w   = (const float*)d_in[20];
    const float* ln_b   = (const float*)d_in[21];
    const float* fc_w   = (const float*)d_in[22];
    const float* fc_b   = (const float*)d_in[23];

    float* ws  = (float*)d_ws;
    float* h     = ws;                               // [21504][128]
    float* ut    = h  + (size_t)MROWS * DM;          // [21504][256]
    float* sp    = ut + (size_t)MROWS * II;          // [21504][40]
    float* q     = sp + (size_t)MROWS * 40;          // [B][NCH][NN][II]
    float* dtsum = q  + (size_t)BB * NCH * NN * II;  // [B][NCH][II]
    short* pool  = (short*)(dtsum + (size_t)BB * NCH * II); // frag pool
    short* hn    = pool + (size_t)FR_TOT * 512;      // [21504][128] bf16

    // one-shot weight swizzle (xp_w + in_w + out_w)
    cvtw_kernel<<<(FR_TOT * 64 + 255) / 256, 256, 0, stream>>>(
        xp_w, in_w, out_w, pool);

    // --- feature fusion (text + img + rank-1 load + bias) ---
    gemm_mfma<false><<<dim3(MROWS / 32, 2), 256, 0, stream>>>(
        x_text, nullptr, Wt, 768, x_img, Wi, 64, b_fuse, x_load, Wl,
        h, DM);

    for (int l = 0; l < LL; ++l) {
        const short* xws   = pool + (size_t)l * XPF * 512;
        const short* inws  = pool + (size_t)(LL * XPF + l * INF) * 512;
        const short* outws = pool + (size_t)(LL * (XPF + INF) + l * OUTF) * 512;
        // rmsnorm'd bf16 A-panel
        hn_kernel<<<MROWS / 4, 256, 0, stream>>>(h, mnorm_w + l * DM, hn);
        // hs-GEMM + conv + x_proj + scanA
        fusedA_kernel<<<dim3(BB, NCH), 256, 0, stream>>>(
            hn, conv_w + l * II * KK, conv_b + l * II, inws, xws,
            in_b + (size_t)l * 2 * II,
            dt_w + l * II * RR, dt_b + l * II, A_log + l * II * NN,
            ut, sp, dtsum, q);
        // gate-GEMM + scanB (serial merged combine) + out_proj (h += ...)
        scanB_kernel<<<dim3(BB, NCH), 256, 0, stream>>>(
            ut, sp, q, dtsum, inws, outws, hn,
            in_b + (size_t)l * 2 * II, out_b + l * DM,
            dt_w + l * II * RR, dt_b + l * II,
            A_log + l * II * NN, Dp + l * II, h);
    }

    final_kernel<<<BB, 64, 0, stream>>>(h, fnorm_w, ln_w, ln_b, fc_w, fc_b,
                                        (float*)d_out);
}

// Round 22
// 180.527 us; speedup vs baseline: 1.0497x; 1.0066x over previous
//
#include <hip/hip_runtime.h>
#include <hip/hip_bf16.h>

// Problem constants
#define BB   128
#define SS   168
#define DM   128
#define LL   2
#define II   256
#define NN   16
#define RR   8
#define KK   4
#define PP   24
#define MROWS (BB*SS)   // 21504
#define NCH  12         // scan chunks
#define TCH  14         // SS / NCH (fits one MFMA M=16 tile)
#define LOG2E 1.4426950408889634f

// bf16 fragment pool: xp_w (24/layer) + in_w (128/layer) + out_w (64/layer)
#define XPF  24
#define INF  128
#define OUTF 64
#define FR_TOT (LL*(XPF+INF+OUTF))   // 432

typedef __attribute__((ext_vector_type(8))) short bf16x8;
typedef __attribute__((ext_vector_type(4))) short bf16x4;
typedef __attribute__((ext_vector_type(4))) float f32x4;

__device__ __forceinline__ float wave_sum(float x) {
#pragma unroll
    for (int off = 32; off > 0; off >>= 1) x += __shfl_xor(x, off);
    return x;
}
__device__ __forceinline__ float fexp2(float x) {   // v_exp_f32 (2^x)
    return __builtin_amdgcn_exp2f(x);
}
__device__ __forceinline__ float siluf(float x) {   // fast: rcp + exp2
    return x * __builtin_amdgcn_rcpf(1.f + fexp2(-LOG2E * x));
}
__device__ __forceinline__ float softplusf(float x) {
    return (x > 20.f) ? x : __logf(1.f + __expf(x));
}
__device__ __forceinline__ short f2bf(float x) {   // RNE f32 -> bf16
    unsigned u = __builtin_bit_cast(unsigned, x);
    u = (u + 0x7FFFu + ((u >> 16) & 1u)) >> 16;
    return (short)u;
}
__device__ __forceinline__ float bf2f(short s) {   // bf16 -> f32 (exact)
    unsigned u = ((unsigned)(unsigned short)s) << 16;
    return __builtin_bit_cast(float, u);
}
// HW packed f32->bf16 (RNE): 4 floats -> bf16x4 (R20-validated)
__device__ __forceinline__ bf16x4 cvt4v(float4 a) {
    unsigned u0, u1;
    asm("v_cvt_pk_bf16_f32 %0, %1, %2" : "=v"(u0) : "v"(a.x), "v"(a.y));
    asm("v_cvt_pk_bf16_f32 %0, %1, %2" : "=v"(u1) : "v"(a.z), "v"(a.w));
    union { unsigned u[2]; bf16x4 v; } r;
    r.u[0] = u0; r.u[1] = u1;
    return r.v;
}
// HW packed f32->bf16 (RNE): 8 floats -> bf16x8 (validated R2/R5/R10)
__device__ __forceinline__ bf16x8 cvt8v(float4 a, float4 b) {
    unsigned u0, u1, u2, u3;
    asm("v_cvt_pk_bf16_f32 %0, %1, %2" : "=v"(u0) : "v"(a.x), "v"(a.y));
    asm("v_cvt_pk_bf16_f32 %0, %1, %2" : "=v"(u1) : "v"(a.z), "v"(a.w));
    asm("v_cvt_pk_bf16_f32 %0, %1, %2" : "=v"(u2) : "v"(b.x), "v"(b.y));
    asm("v_cvt_pk_bf16_f32 %0, %1, %2" : "=v"(u3) : "v"(b.z), "v"(b.w));
    union { unsigned u[4]; bf16x8 v; } r;
    r.u[0] = u0; r.u[1] = u1; r.u[2] = u2; r.u[3] = u3;
    return r.v;
}

// ---------------------------------------------------------------------------
// hn = bf16(h * rsqrt(mean(h^2)+eps) * mnw) — rowscale via wave_sum
// (R12-validated). One wave per row.
// ---------------------------------------------------------------------------
__global__ __launch_bounds__(256)
void hn_kernel(const float* __restrict__ h, const float* __restrict__ mnw,
               short* __restrict__ hn)
{
    const int row  = blockIdx.x * 4 + (threadIdx.x >> 6);
    const int lane = threadIdx.x & 63;
    const float2 v = *(const float2*)&h[(size_t)row * DM + lane * 2];
    const float ss = wave_sum(v.x * v.x + v.y * v.y);
    const float rsv = rsqrtf(ss * (1.f / DM) + 1e-5f);
    const float2 w = *(const float2*)&mnw[lane * 2];
    short2 o;
    o.x = f2bf(v.x * rsv * w.x);
    o.y = f2bf(v.y * rsv * w.y);
    *(short2*)&hn[(size_t)row * DM + lane * 2] = o;
}

// ---------------------------------------------------------------------------
// One-shot weight swizzle to MFMA B-fragment order (R10/R13-validated).
// Pool: [xp l0|l1 (24 ea)][inw l0|l1 (128 ea)][outw l0|l1 (64 ea)].
// ---------------------------------------------------------------------------
__global__ __launch_bounds__(256)
void cvtw_kernel(const float* __restrict__ xw, const float* __restrict__ inw,
                 const float* __restrict__ outw, short* __restrict__ dst)
{
    const int tid = blockIdx.x * 256 + threadIdx.x;
    if (tid >= FR_TOT * 64) return;
    const int lane = tid & 63;
    const int fg = tid >> 6;
    float4 v0 = {0.f, 0.f, 0.f, 0.f}, v1 = {0.f, 0.f, 0.f, 0.f};
    if (fg < LL * XPF) {
        const int l = fg / XPF, f = fg % XPF;
        const int nt = f >> 3, kt = f & 7;
        const int row = nt * 16 + (lane & 15);
        const int kc = kt * 32 + (lane >> 4) * 8;
        if (row < 40) {
            const float* s = xw + ((size_t)l * 40 + row) * II + kc;
            v0 = *(const float4*)s;
            v1 = *(const float4*)(s + 4);
        }
    } else if (fg < LL * (XPF + INF)) {
        const int g = fg - LL * XPF;
        const int l = g / INF, fi = g % INF;
        const int nt = fi >> 2, kt = fi & 3;
        const int row = nt * 16 + (lane & 15);          // 0..511
        const int kc = kt * 32 + (lane >> 4) * 8;       // 0..127
        const float* s = inw + ((size_t)l * 2 * II + row) * DM + kc;
        v0 = *(const float4*)s;
        v1 = *(const float4*)(s + 4);
    } else {
        const int g = fg - LL * (XPF + INF);
        const int l = g / OUTF, fo = g % OUTF;
        const int nt = fo >> 3, kt = fo & 7;            // nt 0..7, kt 0..7
        const int row = nt * 16 + (lane & 15);          // 0..127
        const int kc = kt * 32 + (lane >> 4) * 8;       // 0..255
        const float* s = outw + ((size_t)l * DM + row) * II + kc;
        v0 = *(const float4*)s;
        v1 = *(const float4*)(s + 4);
    }
    *(bf16x8*)(dst + ((size_t)tid) * 8) = cvt8v(v0, v1);
}

// ---------------------------------------------------------------------------
// bf16-MFMA GEMM — R11-exact schedule (fusion only).  R20-validated HW
// v_cvt_pk pack (RNE-identical).
// ---------------------------------------------------------------------------
#define LDT 40
template<bool ACCUM>
__global__ __launch_bounds__(256)
void gemm_mfma(const float* __restrict__ A, const short* __restrict__ Abf,
               const float* __restrict__ W, int K,
               const float* __restrict__ A2, const float* __restrict__ W2, int K2,
               const float* __restrict__ bias,
               const float* __restrict__ r1x, const float* __restrict__ r1w,
               float* __restrict__ C, int ldc)
{
    __shared__ __align__(16) short Asl[32 * LDT];
    __shared__ __align__(16) short Bsl[64 * LDT];
    const int bm = blockIdx.x * 32;
    const int bn = blockIdx.y * 64;
    const int t  = threadIdx.x;
    const int lane = t & 63;
    const int wave = t >> 6;
    const int wr = wave >> 1, wc = wave & 1;
    const int lrow = lane & 15;
    const int lk   = (lane >> 4) * 8;

    f32x4 acc[2];
    acc[0] = (f32x4){0.f, 0.f, 0.f, 0.f};
    acc[1] = (f32x4){0.f, 0.f, 0.f, 0.f};

    const int arow = t >> 3, ak = (t & 7) * 4;    // A: 32 rows x 32 k
    const int brow = t >> 2, bk = (t & 3) * 8;    // B: 64 rows x 32 k

    float av[4], bv[8];
    bf16x4 avb;

#pragma unroll 1
    for (int pass = 0; pass < 2; ++pass) {
        const bool useBf = (pass == 0) && (Abf != nullptr);
        const float* Ap = pass ? A2 : A;
        if (!Ap && !useBf) continue;
        const float* Wp = pass ? W2 : W;
        const int    Kp = pass ? K2 : K;
        const short* abptr = useBf ? Abf + (size_t)(bm + arow) * Kp + ak : nullptr;
        const float* aptr  = useBf ? nullptr : Ap + (size_t)(bm + arow) * Kp + ak;
        const float* bptr = Wp + (size_t)(bn + brow) * Kp + bk;

        // prologue load (k0 = 0)
        if (useBf) avb = *(const bf16x4*)(abptr);
        else       *(float4*)&av[0] = *(const float4*)(aptr);
        *(float4*)&bv[0] = *(const float4*)(bptr);
        *(float4*)&bv[4] = *(const float4*)(bptr + 4);

#pragma unroll 1
        for (int k0 = 0; k0 < Kp; k0 += 32) {
            __syncthreads();   // previous iteration's LDS reads done
            if (useBf) *(bf16x4*)&Asl[arow * LDT + ak] = avb;
            else       *(bf16x4*)&Asl[arow * LDT + ak] = cvt4v(*(const float4*)&av[0]);
            *(bf16x8*)&Bsl[brow * LDT + bk] =
                cvt8v(*(const float4*)&bv[0], *(const float4*)&bv[4]);
            __syncthreads();
            const int kn = k0 + 32;
            if (kn < Kp) {   // prefetch next tile while MFMA runs
                if (useBf) avb = *(const bf16x4*)(abptr + kn);
                else       *(float4*)&av[0] = *(const float4*)(aptr + kn);
                *(float4*)&bv[0] = *(const float4*)(bptr + kn);
                *(float4*)&bv[4] = *(const float4*)(bptr + kn + 4);
            }
            const bf16x8 af = *(const bf16x8*)&Asl[(wr * 16 + lrow) * LDT + lk];
            bf16x8 bfr[2];
#pragma unroll
            for (int ni = 0; ni < 2; ++ni)
                bfr[ni] = *(const bf16x8*)&Bsl[(wc * 32 + ni * 16 + lrow) * LDT + lk];
#pragma unroll
            for (int ni = 0; ni < 2; ++ni)
                acc[ni] = __builtin_amdgcn_mfma_f32_16x16x32_bf16(af, bfr[ni], acc[ni], 0, 0, 0);
        }
    }

    // epilogue
#pragma unroll
    for (int r = 0; r < 4; ++r) {
        const int row = bm + wr * 16 + (lane >> 4) * 4 + r;
        const float xl = r1x ? r1x[row] : 0.f;
#pragma unroll
        for (int ni = 0; ni < 2; ++ni) {
            const int col = bn + wc * 32 + ni * 16 + lrow;
            float v = acc[ni][r];
            if (bias) v += bias[col];
            if (r1x)  v += xl * r1w[col];
            float* cp = &C[(size_t)row * ldc + col];
            if (ACCUM) v += *cp;
            *cp = v;
        }
    }
}

// ---------------------------------------------------------------------------
// Fused hs-GEMM + conv + x_proj(MFMA) + scanA per (b, chunk) — R13/R14/R17
// validated.  R22: u rounded to bf16 ONCE in conv; the rounded value feeds
// uts (scanA, x_proj — which re-rounds idempotently) AND global ut (bf16,
// half the bytes).  scanA/scanB therefore see identical u.
// ---------------------------------------------------------------------------
__global__ __launch_bounds__(256)
void fusedA_kernel(const short* __restrict__ hn, const float* __restrict__ cw,
                   const float* __restrict__ cb, const short* __restrict__ inws,
                   const short* __restrict__ xws, const float* __restrict__ inb,
                   const float* __restrict__ dtw, const float* __restrict__ dtb,
                   const float* __restrict__ A_log,
                   short* __restrict__ ut, float* __restrict__ sp,
                   float* __restrict__ dtsum_g, float* __restrict__ q)
{
    __shared__ float hsl[17][II + 4];    // hs tile incl. 3 halo rows
    __shared__ float uts[TCH][II + 4];   // 14 x 260
    __shared__ float lsp[TCH * 40];
    const int b = blockIdx.x;
    const int ch = blockIdx.y;
    const int i = threadIdx.x;
    const int s0 = ch * TCH;
    const int lane = i & 63;
    const int wv = i >> 6;
    const int lrow = lane & 15;
    const int lkg = (lane >> 4) * 8;
    const int r0 = (lane >> 4) * 4;

    // ---- phase 0: hs tile via MFMA (17 rows x 256 cols, K=128) ----
    {
        const short* hnb = hn + (size_t)b * SS * DM;
#pragma unroll
        for (int mt = 0; mt < 2; ++mt) {
            const int ma = mt * 16 + lrow;       // A row within tile
            const int rga = s0 - 3 + ma;
            const bool va = (ma < 17) && (rga >= 0);
            bf16x8 af[4];
#pragma unroll
            for (int kt = 0; kt < 4; ++kt) {
                if (va) af[kt] = *(const bf16x8*)(hnb + (size_t)rga * DM + kt * 32 + lkg);
                else { bf16x8 z = {0,0,0,0,0,0,0,0}; af[kt] = z; }
            }
#pragma unroll
            for (int j = 0; j < 4; ++j) {
                const int nt = wv * 4 + j;       // 0..15 (hs cols)
                f32x4 acc = (f32x4){0.f, 0.f, 0.f, 0.f};
#pragma unroll
                for (int kt = 0; kt < 4; ++kt) {
                    const bf16x8 bf = *(const bf16x8*)(inws + ((size_t)(nt * 4 + kt) * 64 + lane) * 8);
                    acc = __builtin_amdgcn_mfma_f32_16x16x32_bf16(af[kt], bf, acc, 0, 0, 0);
                }
                const int n = nt * 16 + lrow;
                const float bn_ = inb[n];
#pragma unroll
                for (int r = 0; r < 4; ++r) {
                    const int mrow = mt * 16 + r0 + r;
                    if (mrow < 17) {
                        const int rg = s0 - 3 + mrow;
                        hsl[mrow][n] = (rg < 0) ? 0.f : acc[r] + bn_;
                    }
                }
            }
        }
    }
    __syncthreads();

    // ---- phase 1: conv (reads hsl; halo rows 0..2); u rounded to bf16 ----
    {
        const float4 w = *(const float4*)&cw[i * 4];
        const float bi = cb[i];
        short* up = ut + (size_t)b * SS * II + i;
        float wm3 = hsl[0][i], wm2 = hsl[1][i], wm1 = hsl[2][i];
        for (int s = 0; s < TCH; ++s) {
            const float cur = hsl[s + 3][i];
            float a = fmaf(w.x, wm3, fmaf(w.y, wm2, fmaf(w.z, wm1, fmaf(w.w, cur, bi))));
            const short ub = f2bf(siluf(a));
            const float uv = bf2f(ub);
            up[(s0 + s) * II] = ub;
            uts[s][i] = uv;
            wm3 = wm2; wm2 = wm1; wm1 = cur;
        }
    }
    __syncthreads();

    // ---- phase 2: x_proj via MFMA (waves 0..2) — R10-validated ----
    {
        if (wv < 3) {
            const int srow = lrow;
            const short* wp = xws + ((size_t)(wv * 8) * 64 + lane) * 8;
            f32x4 acc = (f32x4){0.f, 0.f, 0.f, 0.f};
#pragma unroll
            for (int kt = 0; kt < 8; ++kt) {
                const float* up = &uts[0][0] + srow * (II + 4) + kt * 32 + lkg;
                const float4 a0 = *(const float4*)(up);
                const float4 a1 = *(const float4*)(up + 4);
                const bf16x8 af = cvt8v(a0, a1);
                const bf16x8 bf = *(const bf16x8*)(wp + (size_t)kt * 512);
                acc = __builtin_amdgcn_mfma_f32_16x16x32_bf16(af, bf, acc, 0, 0, 0);
            }
            const int col = wv * 16 + lrow;
            if (col < 40) {
#pragma unroll
                for (int r = 0; r < 4; ++r)
                    if (r0 + r < TCH) lsp[(r0 + r) * 40 + col] = acc[r];
            }
        }
    }
    __syncthreads();

    // sp -> global (scanB needs it)
    {
        float* spp = sp + ((size_t)b * SS + s0) * 40;
        for (int idx = i; idx < TCH * 40; idx += 256) spp[idx] = lsp[idx];
    }

    // ---- phase 3: scanA (exp2 with prescaled Ar2) ----
    float dw[8];
    {
        const float4 w0 = *(const float4*)&dtw[i * 8];
        const float4 w1 = *(const float4*)&dtw[i * 8 + 4];
        dw[0]=w0.x; dw[1]=w0.y; dw[2]=w0.z; dw[3]=w0.w;
        dw[4]=w1.x; dw[5]=w1.y; dw[6]=w1.z; dw[7]=w1.w;
    }
    const float bdt = dtb[i];
    float Ar2[NN];
#pragma unroll
    for (int n = 0; n < NN; ++n) Ar2[n] = -LOG2E * __expf(A_log[i * NN + n]);

    float st[NN];
#pragma unroll
    for (int n = 0; n < NN; ++n) st[n] = 0.f;
    float dtsum = 0.f;

    for (int s = 0; s < TCH; ++s) {
        const float uv = uts[s][i];
        const float* r = &lsp[s * 40];
        const float p0 = fmaf(r[1], dw[1], r[0] * dw[0]);
        const float p1 = fmaf(r[3], dw[3], r[2] * dw[2]);
        const float p2 = fmaf(r[5], dw[5], r[4] * dw[4]);
        const float p3 = fmaf(r[7], dw[7], r[6] * dw[6]);
        const float dtv = softplusf(bdt + (p0 + p1) + (p2 + p3));
        const float du = dtv * uv;
        dtsum += dtv;
#pragma unroll
        for (int n = 0; n < NN; ++n) {
            const float a = fexp2(dtv * Ar2[n]);
            st[n] = fmaf(a, st[n], du * r[8 + n]);
        }
    }
    dtsum_g[((size_t)b * NCH + ch) * II + i] = dtsum;
    float* qp = q + (((size_t)b * NCH + ch) * NN) * II + i;
#pragma unroll
    for (int n = 0; n < NN; ++n) qp[n * II] = st[n];
}

// ---------------------------------------------------------------------------
// Scan pass B + gate-GEMM + out_proj (R14/R16/R17-validated structure).
// R19-exact merged combine (serial fma recurrence).  R22: ut is bf16.
// ---------------------------------------------------------------------------
#define YLD 296   // ygl row stride (592B, 16B-aligned; 2-way bank alias, free)
__global__ __launch_bounds__(256)
void scanB_kernel(const short* __restrict__ ut, const float* __restrict__ sp,
                  const float* __restrict__ qloc, const float* __restrict__ dtsum_g,
                  const short* __restrict__ inws,
                  const short* __restrict__ outws, const short* __restrict__ hn,
                  const float* __restrict__ inb, const float* __restrict__ outb,
                  const float* __restrict__ dtw, const float* __restrict__ dtb,
                  const float* __restrict__ A_log, const float* __restrict__ Dp,
                  float* __restrict__ h)
{
    __shared__ float gsl[TCH][II + 4];
    __shared__ float lsp[TCH * 40];
    __shared__ __align__(16) short ygl[16 * YLD];
    const int b = blockIdx.x;
    const int ch = blockIdx.y;
    const int i = threadIdx.x;
    const int s0 = ch * TCH;
    const int lane = i & 63;
    const int wv = i >> 6;
    const int lrow = lane & 15;
    const int lkg = (lane >> 4) * 8;
    const int r0 = (lane >> 4) * 4;

    // ---- issue scan-loop ut loads up front — R16-validated ----
    const short* utp = ut + ((size_t)b * SS + s0) * II + i;
    float uvr[TCH];
#pragma unroll
    for (int s = 0; s < TCH; ++s) uvr[s] = bf2f(utp[s * II]);

    // Ar2 (needed for the merged combine recurrence)
    float Ar2[NN];
#pragma unroll
    for (int n = 0; n < NN; ++n) Ar2[n] = -LOG2E * __expf(A_log[i * NN + n]);

    // ---- merged combine: st = q_init[ch] via the exact combine recurrence
    //      (c = 0..ch-1 ascending, cur = fma(Pv, cur, qv)) — R19-validated ----
    float st[NN];
#pragma unroll
    for (int n = 0; n < NN; ++n) st[n] = 0.f;
    {
        const float* dsb = dtsum_g + ((size_t)b * NCH) * II + i;
        const float* qb  = qloc + (((size_t)b * NCH) * NN) * II + i;
        for (int c = 0; c < ch; ++c) {
            const float dsc = dsb[(size_t)c * II];
            const float* qc = qb + (size_t)c * NN * II;
#pragma unroll
            for (int n = 0; n < NN; ++n)
                st[n] = fmaf(fexp2(Ar2[n] * dsc), st[n], qc[(size_t)n * II]);
        }
    }

    // zero ygl rows 14,15 (A-rows beyond TCH)
    ygl[14 * YLD + i] = 0; ygl[15 * YLD + i] = 0;

    // ---- gate tile via MFMA (14 rows x 256 cols, K=128) — R13-validated ----
    {
        const short* hnb = hn + (size_t)b * SS * DM;
        const bool va = (lrow < TCH);
        const int rga = s0 + lrow;
        bf16x8 af[4];
#pragma unroll
        for (int kt = 0; kt < 4; ++kt) {
            if (va) af[kt] = *(const bf16x8*)(hnb + (size_t)rga * DM + kt * 32 + lkg);
            else { bf16x8 z = {0,0,0,0,0,0,0,0}; af[kt] = z; }
        }
#pragma unroll
        for (int j = 0; j < 4; ++j) {
            const int nt = 16 + wv * 4 + j;      // gate col-tiles 16..31
            f32x4 acc = (f32x4){0.f, 0.f, 0.f, 0.f};
#pragma unroll
            for (int kt = 0; kt < 4; ++kt) {
                const bf16x8 bf = *(const bf16x8*)(inws + ((size_t)(nt * 4 + kt) * 64 + lane) * 8);
                acc = __builtin_amdgcn_mfma_f32_16x16x32_bf16(af[kt], bf, acc, 0, 0, 0);
            }
            const int n = (nt - 16) * 16 + lrow;
            const float bn_ = inb[256 + n];
#pragma unroll
            for (int r = 0; r < 4; ++r)
                if (r0 + r < TCH) gsl[r0 + r][n] = acc[r] + bn_;
        }
    }

    // sp -> LDS
    {
        const float* spp = sp + ((size_t)b * SS + s0) * 40;
        for (int idx = i; idx < TCH * 40; idx += 256) lsp[idx] = spp[idx];
    }
    float dw[8];
    {
        const float4 w0 = *(const float4*)&dtw[i * 8];
        const float4 w1 = *(const float4*)&dtw[i * 8 + 4];
        dw[0]=w0.x; dw[1]=w0.y; dw[2]=w0.z; dw[3]=w0.w;
        dw[4]=w1.x; dw[5]=w1.y; dw[6]=w1.z; dw[7]=w1.w;
    }
    const float bdt = dtb[i];
    const float Dv = Dp[i];
    __syncthreads();

    for (int s = 0; s < TCH; ++s) {
        const float uv = uvr[s];
        const float* r = &lsp[s * 40];
        const float p0 = fmaf(r[1], dw[1], r[0] * dw[0]);
        const float p1 = fmaf(r[3], dw[3], r[2] * dw[2]);
        const float p2 = fmaf(r[5], dw[5], r[4] * dw[4]);
        const float p3 = fmaf(r[7], dw[7], r[6] * dw[6]);
        const float dtv = softplusf(bdt + (p0 + p1) + (p2 + p3));
        const float du = dtv * uv;
        float y0 = 0.f, y1 = 0.f, y2 = 0.f, y3 = 0.f;
#pragma unroll
        for (int n = 0; n < NN; n += 4) {
            const float a0 = fexp2(dtv * Ar2[n + 0]);
            const float a1 = fexp2(dtv * Ar2[n + 1]);
            const float a2 = fexp2(dtv * Ar2[n + 2]);
            const float a3 = fexp2(dtv * Ar2[n + 3]);
            st[n + 0] = fmaf(a0, st[n + 0], du * r[8 + n + 0]);
            st[n + 1] = fmaf(a1, st[n + 1], du * r[8 + n + 1]);
            st[n + 2] = fmaf(a2, st[n + 2], du * r[8 + n + 2]);
            st[n + 3] = fmaf(a3, st[n + 3], du * r[8 + n + 3]);
            y0 = fmaf(st[n + 0], r[24 + n + 0], y0);
            y1 = fmaf(st[n + 1], r[24 + n + 1], y1);
            y2 = fmaf(st[n + 2], r[24 + n + 2], y2);
            y3 = fmaf(st[n + 3], r[24 + n + 3], y3);
        }
        const float yv = (y0 + y1) + (y2 + y3) + uv * Dv;
        ygl[s * YLD + i] = f2bf(yv * siluf(gsl[s][i]));
    }
    __syncthreads();   // ygl complete

    // ---- out_proj via MFMA: h[s0..s0+13][0..127] += ygl @ out_w^T + b ----
    {
        bf16x8 af[8];
#pragma unroll
        for (int kt = 0; kt < 8; ++kt)
            af[kt] = *(const bf16x8*)&ygl[lrow * YLD + kt * 32 + lkg];
#pragma unroll
        for (int j = 0; j < 2; ++j) {
            const int nt = wv * 2 + j;           // 0..7 (128 h cols)
            f32x4 acc = (f32x4){0.f, 0.f, 0.f, 0.f};
#pragma unroll
            for (int kt = 0; kt < 8; ++kt) {
                const bf16x8 bf = *(const bf16x8*)(outws + ((size_t)(nt * 8 + kt) * 64 + lane) * 8);
                acc = __builtin_amdgcn_mfma_f32_16x16x32_bf16(af[kt], bf, acc, 0, 0, 0);
            }
            const int col = nt * 16 + lrow;
            const float bo = outb[col];
#pragma unroll
            for (int r = 0; r < 4; ++r) {
                const int srow = r0 + r;
                if (srow < TCH) {
                    float* hp = &h[((size_t)b * SS + s0 + srow) * DM + col];
                    *hp += acc[r] + bo;
                }
            }
        }
    }
}

// ---------------------------------------------------------------------------
// Final head: rmsnorm(h[b,S-1,:]) -> layernorm -> fc -> out[b,p]
// ---------------------------------------------------------------------------
__global__ __launch_bounds__(64)
void final_kernel(const float* __restrict__ h, const float* __restrict__ fnw,
                  const float* __restrict__ lnw, const float* __restrict__ lnb,
                  const float* __restrict__ fcw, const float* __restrict__ fcb,
                  float* __restrict__ out)
{
    __shared__ float last[DM];
    const int b = blockIdx.x;
    const int lane = threadIdx.x;
    const float* hp = &h[((size_t)b * SS + (SS - 1)) * DM];
    const float2 v = *(const float2*)&hp[lane * 2];
    const float ss = wave_sum(v.x * v.x + v.y * v.y);
    const float sc = rsqrtf(ss * (1.f / DM) + 1e-5f);
    const float2 fw = *(const float2*)&fnw[lane * 2];
    const float t0 = v.x * sc * fw.x, t1 = v.y * sc * fw.y;
    const float m = wave_sum(t0 + t1) * (1.f / DM);
    const float d0 = t0 - m, d1 = t1 - m;
    const float var = wave_sum(d0 * d0 + d1 * d1) * (1.f / DM);
    const float iv = rsqrtf(var + 1e-5f);
    const float2 lw = *(const float2*)&lnw[lane * 2];
    const float2 lb = *(const float2*)&lnb[lane * 2];
    last[lane * 2]     = d0 * iv * lw.x + lb.x;
    last[lane * 2 + 1] = d1 * iv * lw.y + lb.y;
    __syncthreads();
    if (lane < PP) {
        float a = fcb[lane];
#pragma unroll 8
        for (int d = 0; d < DM; ++d) a = fmaf(last[d], fcw[lane * DM + d], a);
        out[b * PP + lane] = a;
    }
}

// ---------------------------------------------------------------------------
extern "C" void kernel_launch(void* const* d_in, const int* in_sizes, int n_in,
                              void* d_out, int out_size, void* d_ws, size_t ws_size,
                              hipStream_t stream)
{
    (void)in_sizes; (void)n_in; (void)out_size; (void)ws_size;
    const float* x_load = (const float*)d_in[0];
    const float* x_img  = (const float*)d_in[1];
    const float* x_text = (const float*)d_in[2];
    const float* Wl     = (const float*)d_in[3];
    const float* Wi     = (const float*)d_in[4];
    const float* Wt     = (const float*)d_in[5];
    const float* b_fuse = (const float*)d_in[6];
    const float* mnorm_w= (const float*)d_in[7];
    const float* in_w   = (const float*)d_in[8];
    const float* in_b   = (const float*)d_in[9];
    const float* conv_w = (const float*)d_in[10];
    const float* conv_b = (const float*)d_in[11];
    const float* xp_w   = (const float*)d_in[12];
    const float* dt_w   = (const float*)d_in[13];
    const float* dt_b   = (const float*)d_in[14];
    const float* A_log  = (const float*)d_in[15];
    const float* Dp     = (const float*)d_in[16];
    const float* out_w  = (const float*)d_in[17];
    const float* out_b  = (const float*)d_in[18];
    const float* fnorm_w= (const float*)d_in[19];
    const float* ln_w   = (const float*)d_in[20];
    const float* ln_b   = (const float*)d_in[21];
    const float* fc_w   = (const float*)d_in[22];
    const float* fc_b   = (const float*)d_in[23];

    float* ws  = (float*)d_ws;
    float* h     = ws;                               // [21504][128] f32
    short* utb   = (short*)(h + (size_t)MROWS * DM); // [21504][256] bf16
    float* sp    = (float*)(utb + (size_t)MROWS * II); // [21504][40]
    float* q     = sp + (size_t)MROWS * 40;          // [B][NCH][NN][II]
    float* dtsum = q  + (size_t)BB * NCH * NN * II;  // [B][NCH][II]
    short* pool  = (short*)(dtsum + (size_t)BB * NCH * II); // frag pool
    short* hn    = pool + (size_t)FR_TOT * 512;      // [21504][128] bf16

    // one-shot weight swizzle (xp_w + in_w + out_w)
    cvtw_kernel<<<(FR_TOT * 64 + 255) / 256, 256, 0, stream>>>(
        xp_w, in_w, out_w, pool);

    // --- feature fusion (text + img + rank-1 load + bias) ---
    gemm_mfma<false><<<dim3(MROWS / 32, 2), 256, 0, stream>>>(
        x_text, nullptr, Wt, 768, x_img, Wi, 64, b_fuse, x_load, Wl,
        h, DM);

    for (int l = 0; l < LL; ++l) {
        const short* xws   = pool + (size_t)l * XPF * 512;
        const short* inws  = pool + (size_t)(LL * XPF + l * INF) * 512;
        const short* outws = pool + (size_t)(LL * (XPF + INF) + l * OUTF) * 512;
        // rmsnorm'd bf16 A-panel
        hn_kernel<<<MROWS / 4, 256, 0, stream>>>(h, mnorm_w + l * DM, hn);
        // hs-GEMM + conv + x_proj + scanA (ut stored bf16)
        fusedA_kernel<<<dim3(BB, NCH), 256, 0, stream>>>(
            hn, conv_w + l * II * KK, conv_b + l * II, inws, xws,
            in_b + (size_t)l * 2 * II,
            dt_w + l * II * RR, dt_b + l * II, A_log + l * II * NN,
            utb, sp, dtsum, q);
        // gate-GEMM + scanB (serial merged combine) + out_proj (h += ...)
        scanB_kernel<<<dim3(BB, NCH), 256, 0, stream>>>(
            utb, sp, q, dtsum, inws, outws, hn,
            in_b + (size_t)l * 2 * II, out_b + l * DM,
            dt_w + l * II * RR, dt_b + l * II,
            A_log + l * II * NN, Dp + l * II, h);
    }

    final_kernel<<<BB, 64, 0, stream>>>(h, fnorm_w, ln_w, ln_b, fc_w, fc_b,
                                        (float*)d_out);
}